// Round 3
// baseline (338.654 us; speedup 1.0000x reference)
//
#include <hip/hip_runtime.h>
#include <stdint.h>

typedef __attribute__((ext_vector_type(8))) short short8;
typedef __attribute__((ext_vector_type(8))) unsigned short ushort8;
typedef __attribute__((ext_vector_type(4))) float f32x4;

#define LDST 40     // 32 + 8 pad: 80B row stride, 16B-aligned b128 frags, <=2-way bank alias
#define XPST 66     // xp tile [t][r] stride (scalar access, conflict-free)

static __device__ __forceinline__ unsigned short f2bf(float f) {
    union { float f; uint32_t u; } v; v.f = f;
    uint32_t u = v.u;
    u += 0x7fffu + ((u >> 16) & 1u);   // RNE
    return (unsigned short)(u >> 16);
}

// ---------------- W transpose+convert: Wt[n][k] bf16 from W[k][n] fp32 ----------------
__global__ __launch_bounds__(256)
void wt_kernel(const float* __restrict__ W, unsigned short* __restrict__ Wt)
{
    __shared__ float s[32][33];
    const int tx = threadIdx.x;          // 0..31
    const int ty = threadIdx.y;          // 0..7
    const int kBase = blockIdx.x * 32;
    const int nBase = blockIdx.y * 32;
    #pragma unroll
    for (int j = 0; j < 4; ++j)
        s[ty + 8 * j][tx] = W[(size_t)(kBase + ty + 8 * j) * 512 + nBase + tx];
    __syncthreads();
    #pragma unroll
    for (int j = 0; j < 4; ++j)
        Wt[(size_t)(nBase + ty + 8 * j) * 512 + kBase + tx] = f2bf(s[tx][ty + 8 * j]);
}

// ---------------- fused GEMM + IndRNN scan ----------------
// Grid 512 = 64 b x 8 rb. Block owns out[b][:][rb*64 .. rb*64+64].
// Per 128-t tile: MFMA (M=128,N=64,K=512) -> xp tile in LDS -> wave0 scans 128 steps.
__global__ __launch_bounds__(256, 2)
void fused_kernel(const float* __restrict__ X, const unsigned short* __restrict__ Wt,
                  const float* __restrict__ bias, const float* __restrict__ u,
                  float* __restrict__ out)
{
    __shared__ unsigned short As[2][128 * LDST];  // [t-row][k] bf16
    __shared__ unsigned short Bs[2][64 * LDST];   // [r-row][k] bf16
    __shared__ float xpL[128 * XPST];             // [t][r] fp32

    const int tid = threadIdx.x;
    const int bx  = blockIdx.x;
    const int b   = bx & 63;     // blocks sharing b are 64 apart -> same XCD (%8) -> L2 reuse of X
    const int rb  = bx >> 6;     // 0..7

    const int lane  = tid & 63;
    const int wave  = tid >> 6;
    const int m16   = lane & 15;
    const int quad  = lane >> 4;
    const int waveM = wave & 1;    // 2 waves over M(=t) 128 -> 64 each
    const int waveN = wave >> 1;   // 2 waves over N(=r) 64  -> 32 each

    // staging thread->element maps
    const int aRow8 = tid >> 3;    // 0..31 (A: +p*32)
    const int aK    = (tid & 7) * 4;
    const int bRow  = tid >> 2;    // 0..63
    const int bK    = (tid & 3) * 8;

    // scan state (wave 0 only uses it, but harmless everywhere)
    const float ur = u[rb * 64 + (tid & 63)];
    const float br = bias[rb * 64 + (tid & 63)];
    float h = 1.0f;

    f32x4 acc[4][2] = {};
    float4 aF[4];
    ushort8 bF;

    const float* xB = X + (size_t)b * 1024 * 512;
    const unsigned short* wB = Wt + (size_t)(rb * 64) * 512;

    // bootstrap prefetch (tile 0, k-iter 0)
    #pragma unroll
    for (int p = 0; p < 4; ++p)
        aF[p] = *(const float4*)(xB + (size_t)(p * 32 + aRow8) * 512 + aK);
    bF = *(const ushort8*)(wB + (size_t)bRow * 512 + bK);

    for (int tt = 0; tt < 8; ++tt) {
        for (int ki = 0; ki < 16; ++ki) {
            const int buf = ki & 1;
            // ---- regs -> LDS (convert A fp32->bf16) ----
            #pragma unroll
            for (int p = 0; p < 4; ++p) {
                ushort4 us;
                us.x = f2bf(aF[p].x); us.y = f2bf(aF[p].y);
                us.z = f2bf(aF[p].z); us.w = f2bf(aF[p].w);
                *(ushort4*)&As[buf][(p * 32 + aRow8) * LDST + aK] = us;
            }
            *(ushort8*)&Bs[buf][bRow * LDST + bK] = bF;
            __syncthreads();

            // ---- prefetch next k-iter (crosses tile boundary to hide bubble) ----
            int nki = ki + 1, ntt = tt;
            if (nki == 16) { nki = 0; ++ntt; }
            if (ntt < 8) {
                const float* xT = xB + (size_t)(ntt * 128) * 512 + (size_t)nki * 32;
                #pragma unroll
                for (int p = 0; p < 4; ++p)
                    aF[p] = *(const float4*)(xT + (size_t)(p * 32 + aRow8) * 512 + aK);
                bF = *(const ushort8*)(wB + (size_t)bRow * 512 + (size_t)nki * 32 + bK);
            }

            // ---- fragments + MFMA ----
            short8 af[4], bf2[2];
            #pragma unroll
            for (int mi = 0; mi < 4; ++mi)
                af[mi] = *(const short8*)&As[buf][(waveM * 64 + mi * 16 + m16) * LDST + quad * 8];
            #pragma unroll
            for (int ni = 0; ni < 2; ++ni)
                bf2[ni] = *(const short8*)&Bs[buf][(waveN * 32 + ni * 16 + m16) * LDST + quad * 8];
            #pragma unroll
            for (int mi = 0; mi < 4; ++mi)
                #pragma unroll
                for (int ni = 0; ni < 2; ++ni)
                    acc[mi][ni] = __builtin_amdgcn_mfma_f32_16x16x32_bf16(
                        af[mi], bf2[ni], acc[mi][ni], 0, 0, 0);
            __syncthreads();
        }

        // ---- epilogue: acc -> xpL[t][r]; C/D layout (m89): col=lane&15, row=quad*4+reg ----
        #pragma unroll
        for (int mi = 0; mi < 4; ++mi) {
            const int t0 = waveM * 64 + mi * 16 + quad * 4;
            #pragma unroll
            for (int ni = 0; ni < 2; ++ni) {
                const int r = waveN * 32 + ni * 16 + m16;
                #pragma unroll
                for (int rr = 0; rr < 4; ++rr)
                    xpL[(t0 + rr) * XPST + r] = acc[mi][ni][rr];
                acc[mi][ni] = (f32x4){0.f, 0.f, 0.f, 0.f};
            }
        }
        __syncthreads();

        // ---- scan: wave 0, thread r, 128 sequential steps out of LDS ----
        if (tid < 64) {
            float* o = out + ((size_t)b * 1024 + (size_t)tt * 128) * 512 + rb * 64 + tid;
            for (int t0 = 0; t0 < 128; t0 += 16) {
                float v[16];
                #pragma unroll
                for (int j = 0; j < 16; ++j) v[j] = xpL[(t0 + j) * XPST + tid] + br;
                #pragma unroll
                for (int j = 0; j < 16; ++j) {
                    h = fmaxf(fmaf(ur, h, v[j]), 0.0f);
                    o[(size_t)(t0 + j) * 512] = h;
                }
            }
        }
        // next tile's k-loop barriers order xpL reuse; no extra barrier needed
    }
}

extern "C" void kernel_launch(void* const* d_in, const int* in_sizes, int n_in,
                              void* d_out, int out_size, void* d_ws, size_t ws_size,
                              hipStream_t stream) {
    const float* x = (const float*)d_in[0];   // [64,1024,512]
    const float* W = (const float*)d_in[1];   // [512,512]
    const float* u = (const float*)d_in[2];   // [512]
    const float* b = (const float*)d_in[3];   // [512]
    float* out = (float*)d_out;               // [64,1024,512] fp32

    unsigned short* Wt = (unsigned short*)d_ws;   // 512 KB bf16 (ws >= 512 KB verified R2)

    dim3 tgrid(16, 16), tblk(32, 8);
    wt_kernel<<<tgrid, tblk, 0, stream>>>(W, Wt);
    fused_kernel<<<512, 256, 0, stream>>>(x, Wt, b, u, out);
}